// Round 2
// baseline (497.210 us; speedup 1.0000x reference)
//
#include <hip/hip_runtime.h>
#include <stdint.h>

#define N_PART   100000
#define N_FRAMES 500

__device__ __forceinline__ uint32_t rotl32(uint32_t v, int d) {
    return (v << d) | (v >> (32 - d));
}

// JAX threefry2x32, 20 rounds, exact port of jax/_src/prng.py
#define TF_ROUND(r) { x0 += x1; x1 = rotl32(x1, (r)); x1 ^= x0; }

__device__ __forceinline__ void tf2x32(uint32_t k0, uint32_t k1,
                                       uint32_t x0, uint32_t x1,
                                       uint32_t &o0, uint32_t &o1) {
    const uint32_t k2 = k0 ^ k1 ^ 0x1BD11BDAu;
    x0 += k0; x1 += k1;
    TF_ROUND(13) TF_ROUND(15) TF_ROUND(26) TF_ROUND(6)
    x0 += k1; x1 += k2 + 1u;
    TF_ROUND(17) TF_ROUND(29) TF_ROUND(16) TF_ROUND(24)
    x0 += k2; x1 += k0 + 2u;
    TF_ROUND(13) TF_ROUND(15) TF_ROUND(26) TF_ROUND(6)
    x0 += k0; x1 += k1 + 3u;
    TF_ROUND(17) TF_ROUND(29) TF_ROUND(16) TF_ROUND(24)
    x0 += k1; x1 += k2 + 4u;
    TF_ROUND(13) TF_ROUND(15) TF_ROUND(26) TF_ROUND(6)
    x0 += k2; x1 += k0 + 5u;
    o0 = x0; o1 = x1;
}

// partitionable random_bits(key, 32, shape): bits[idx] = o0^o1 of tf(key, (0, idx))
__device__ __forceinline__ float uniform_from_bits(uint32_t bits) {
    // bitcast((bits>>9) | 0x3f800000) - 1.0f, exact per JAX _uniform
    return __uint_as_float((bits >> 9) | 0x3f800000u) - 1.0f;
}

__global__ __launch_bounds__(256)
void hmm_kernel(const float* __restrict__ initial,
                const int* __restrict__ seed_ptr,
                float* __restrict__ out) {
    __shared__ uint32_t skey0[N_FRAMES];
    __shared__ uint32_t skey1[N_FRAMES];
    __shared__ float sp;

    const int tid = threadIdx.x;
    const uint32_t seed_lo = (uint32_t)seed_ptr[0];
    const uint32_t seed_hi = 0u;  // threefry_seed: k1 = seed >> 32 (0 for int32 seeds)

    // key = (seed_hi, seed_lo)
    // split(key) foldlike: kp = tf(key,(0,0)), ks = tf(key,(0,1))
    uint32_t ks0, ks1;
    tf2x32(seed_hi, seed_lo, 0u, 1u, ks0, ks1);

    // keys[t] = tf(ks, (0, t)) for t in [0,500)
    for (int t = tid; t < N_FRAMES; t += blockDim.x) {
        uint32_t a, b;
        tf2x32(ks0, ks1, 0u, (uint32_t)t, a, b);
        skey0[t] = a;
        skey1[t] = b;
    }
    if (tid == 0) {
        uint32_t kp0, kp1;
        tf2x32(seed_hi, seed_lo, 0u, 0u, kp0, kp1);
        // uniform(kp, ()): size 1, idx 0 -> bits = o0^o1 of tf(kp,(0,0))
        uint32_t b0, b1;
        tf2x32(kp0, kp1, 0u, 0u, b0, b1);
        sp = uniform_from_bits(b0 ^ b1) * 0.001f;
    }
    __syncthreads();

    const int n = blockIdx.x * blockDim.x + tid;
    if (n >= N_PART) return;

    const float p = sp;               // P(flip | state==1)
    const float p0 = 0.2f;            // P(flip | state==0), jnp.float32(0.2)

    // initial one-hot [N,2] -> integer state
    int s = (initial[2 * n + 1] > 0.5f) ? 1 : 0;

    float2* __restrict__ outv = (float2*)out;

    for (int t = 0; t < N_FRAMES; ++t) {
        const uint32_t k0 = skey0[t];
        const uint32_t k1 = skey1[t];
        // uniform for flat index 2n+s of shape (N,2) under keys[t]
        uint32_t b0, b1;
        tf2x32(k0, k1, 0u, (uint32_t)(2 * n + s), b0, b1);
        const float u = uniform_from_bits(b0 ^ b1);
        const float thr = s ? p : p0;
        s ^= (u < thr) ? 1 : 0;
        const float2 o = s ? make_float2(0.0f, 1.0f) : make_float2(1.0f, 0.0f);
        outv[(size_t)t * N_PART + n] = o;
    }
}

extern "C" void kernel_launch(void* const* d_in, const int* in_sizes, int n_in,
                              void* d_out, int out_size, void* d_ws, size_t ws_size,
                              hipStream_t stream) {
    const float* initial = (const float*)d_in[0];
    const int*   seed    = (const int*)d_in[1];
    float*       out     = (float*)d_out;

    const int block = 256;
    const int grid = (N_PART + block - 1) / block;
    hmm_kernel<<<grid, block, 0, stream>>>(initial, seed, out);
}